// Round 7
// baseline (188.808 us; speedup 1.0000x reference)
//
#include <hip/hip_runtime.h>
#include <hip/hip_fp16.h>
#include <math.h>

#define N_MESH   5151
#define NB       8
#define TT       2048
#define HID      256
#define NLAYERS  3
#define NCHUNK   16
#define CHUNK    128           // TT / NCHUNK
#define TSTR     104           // table row stride (ushort)
#define NPAD     6144          // 6 blocks * 1024
#define NBLK1    6             // scan n-blocks (1024 pts each, 4/thread)
#define NBLK3    6
#define K1_GRID  (NBLK1 * NB * NCHUNK)   // 768
#define MLP_RPB  7             // MLP rows per k1 block (768*7 = 5376 >= 5151)

// k1 smem layout (bytes)
#define OFF_SGV   528          // hs2 = 132 floats @0
#define OFF_TAB   1056         // sgv = 128 floats @528
#define OFF_HA    27680        // tab = 128*104 ushort = 26624 B
#define SMEM1     34848        // hA = 7*256 floats = 7168 B
#define SMEM3     27680        // k3: no hA

// ws layout (floats)
#define WS_DENSITY 0           // 5151
#define WS_SUM     5184        // 1
#define WS_PART    6144        // NB*NBLK3*8*TT = 786432 -> ends 792576
#define WS_PQ      792576      // NCHUNK*NB*NPAD*2 = 1572864 -> ends 2365440

// out layout (floats)
#define OUT_BNORM  0           // 16384
#define OUT_DENSB  16384       // 41208
#define OUT_M      57592       // 16384
#define OUT_S0     73976       // 41208
#define OUT_MESHB  115184      // 82416

__device__ __forceinline__ float sigmoid_fast(float x) {
    float e = __expf(-x);
    return __builtin_amdgcn_rcpf(1.0f + e);
}

__device__ __forceinline__ float4 fma4s(float s, float4 w, float4 a) {
    a.x = fmaf(s, w.x, a.x); a.y = fmaf(s, w.y, a.y);
    a.z = fmaf(s, w.z, a.z); a.w = fmaf(s, w.w, a.w);
    return a;
}

// Direction-resolved A-table (fp16), linear conflict-free build.
// inc: A = 1/(1+exp(1000h-10g)); dec: A = 1/(1+exp(10g-1000h))
__device__ __forceinline__ void build_table(int tid, int nt, const float* hs2,
                                            float* sgv, unsigned short* tab)
{
    if (tid < CHUNK) sgv[tid] = (hs2[tid + 1] >= hs2[tid]) ? 1.0f : -1.0f;
    for (int idx = tid; idx < CHUNK * TSTR; idx += nt) {
        int t = idx / TSTR;            // const-div -> magic mul
        int g = idx - t * TSTR;
        float ht = hs2[t + 1];
        bool inc = (ht >= hs2[t]);
        float bx = ht * 1000.0f;
        float y = inc ? fmaf(-10.f, (float)g, bx) : fmaf(10.f, (float)g, -bx);
        float A = __builtin_amdgcn_rcpf(1.0f + __expf(y));
        tab[idx] = __half_as_ushort(__float2half(A));
    }
}

// ---------------------------------------------------------------------------
// k1: 768 blocks x 320 threads. Waves 0-3 (tid<256): scan phase1 for one
// (nb,b,chunk). Wave 4 (tid>=256): density MLP for 7 rows, in-wave 2-way
// K-split, W streamed from L2. Exactly 2 barriers, on a uniform path.
// ---------------------------------------------------------------------------
__global__ __launch_bounds__(320, 4) void k1_fused(
    const float* __restrict__ dec, const float* __restrict__ y0,
    const float* __restrict__ mesh, const float* __restrict__ Win,
    const float* __restrict__ bin,  const float* __restrict__ Wblk,
    const float* __restrict__ bblk, const float* __restrict__ Wout,
    const float* __restrict__ bout, float* __restrict__ ws_density,
    float2* __restrict__ PQ)
{
    __shared__ __align__(16) char smem[SMEM1];
    float* hs2 = (float*)smem;
    float* sgv = (float*)(smem + OFF_SGV);
    unsigned short* tab = (unsigned short*)(smem + OFF_TAB);
    float* hA  = (float*)(smem + OFF_HA);

    const int tid = threadIdx.x;
    const int sb = blockIdx.x;
    const int nb = sb % NBLK1;
    const int rem = sb / NBLK1;
    const int b = rem & 7;
    const int c = rem >> 3;
    const int t0 = c * CHUNK;

    const int lane = tid & 63;
    const int l32  = lane & 31;
    const int half = lane >> 5;
    const int c0a  = l32 * 4;
    const int c0b  = c0a + 128;
    const int khalf = half * 128;
    const int row0 = sb * MLP_RPB;

    if (tid < CHUNK) hs2[tid + 1] = dec[b * TT + t0 + tid];
    if (tid == 0) hs2[0] = (c == 0) ? y0[b] : dec[b * TT + t0 - 1];

    int ga[4], gb[4];
    if (tid < 256) {
        // scan waves: load thresholds
#pragma unroll
        for (int q = 0; q < 4; ++q) {
            int n = nb * 1024 + q * 256 + tid;
            if (n < N_MESH) {
                gb[q] = (int)(mesh[2 * n]     * 100.0f + 0.5f);
                ga[q] = (int)(mesh[2 * n + 1] * 100.0f + 0.5f);
            } else { ga[q] = 0; gb[q] = 0; }
        }
    } else {
        // MLP wave: input layer -> hA
        float4 wiA0 = *(const float4*)&Win[c0a];
        float4 wiB0 = *(const float4*)&Win[c0b];
        float4 wiA1 = *(const float4*)&Win[HID + c0a];
        float4 wiB1 = *(const float4*)&Win[HID + c0b];
        float4 biA  = *(const float4*)&bin[c0a];
        float4 biB  = *(const float4*)&bin[c0b];
#pragma unroll
        for (int j = 0; j < MLP_RPB; ++j) {
            int gr = row0 + j;
            float m0 = 0.f, m1 = 0.f;
            if (gr < N_MESH) { m0 = mesh[2 * gr]; m1 = mesh[2 * gr + 1]; }
            float4 ha, hb;
            ha.x = fmaxf(fmaf(m0, wiA0.x, fmaf(m1, wiA1.x, biA.x)), 0.f);
            ha.y = fmaxf(fmaf(m0, wiA0.y, fmaf(m1, wiA1.y, biA.y)), 0.f);
            ha.z = fmaxf(fmaf(m0, wiA0.z, fmaf(m1, wiA1.z, biA.z)), 0.f);
            ha.w = fmaxf(fmaf(m0, wiA0.w, fmaf(m1, wiA1.w, biA.w)), 0.f);
            hb.x = fmaxf(fmaf(m0, wiB0.x, fmaf(m1, wiB1.x, biB.x)), 0.f);
            hb.y = fmaxf(fmaf(m0, wiB0.y, fmaf(m1, wiB1.y, biB.y)), 0.f);
            hb.z = fmaxf(fmaf(m0, wiB0.z, fmaf(m1, wiB1.z, biB.z)), 0.f);
            hb.w = fmaxf(fmaf(m0, wiB0.w, fmaf(m1, wiB1.w, biB.w)), 0.f);
            *(float4*)&hA[j * HID + c0a] = ha;
            *(float4*)&hA[j * HID + c0b] = hb;
        }
    }
    __syncthreads();
    build_table(tid, 320, hs2, sgv, tab);
    __syncthreads();

    if (tid < 256) {
        // ------------------ scan phase 1 ------------------
        float P[4] = {1.f, 1.f, 1.f, 1.f};
        float R[4];
        float gprev = sgv[0];
#pragma unroll
        for (int q = 0; q < 4; ++q) R[q] = -gprev;

        for (int tb = 0; tb < CHUNK; tb += 16) {
#pragma unroll
            for (int j = 0; j < 16; ++j) {
                int t = tb + j;
                float sgt = sgv[t];
                float dl = gprev - sgt;      // 0 or +-2, wave-uniform
                gprev = sgt;
                bool inc = sgt > 0.0f;
                int base = t * TSTR;
#pragma unroll
                for (int q = 0; q < 4; ++q) {
                    int ig = inc ? ga[q] : gb[q];
                    float A = __half2float(__ushort_as_half(tab[base + ig]));
                    float r = R[q] + dl;
                    P[q] *= A;
                    R[q] = r * A;
                }
            }
        }
        size_t basew = ((size_t)(c * NB + b)) * NPAD;
#pragma unroll
        for (int q = 0; q < 4; ++q) {
            int n = nb * 1024 + q * 256 + tid;
            float2 v; v.x = P[q]; v.y = R[q] + gprev;
            PQ[basew + n] = v;
        }
    } else {
        // ------------------ density MLP, 3 residual layers ------------------
        for (int L = 0; L < NLAYERS; ++L) {
            const float* W = Wblk + (size_t)L * HID * HID + (size_t)khalf * HID;
            float4 aA[MLP_RPB], aB[MLP_RPB];
#pragma unroll
            for (int j = 0; j < MLP_RPB; ++j) {
                aA[j] = make_float4(0.f, 0.f, 0.f, 0.f);
                aB[j] = make_float4(0.f, 0.f, 0.f, 0.f);
            }
#pragma unroll 2
            for (int kk = 0; kk < 128; kk += 2) {
                const float* W0 = W + (size_t)kk * HID;
                float4 wA0 = *(const float4*)&W0[c0a];
                float4 wB0 = *(const float4*)&W0[c0b];
                float4 wA1 = *(const float4*)&W0[HID + c0a];
                float4 wB1 = *(const float4*)&W0[HID + c0b];
#pragma unroll
                for (int j = 0; j < MLP_RPB; ++j) {
                    float2 hj = *(const float2*)&hA[j * HID + khalf + kk];
                    aA[j] = fma4s(hj.x, wA0, aA[j]);
                    aB[j] = fma4s(hj.x, wB0, aB[j]);
                    aA[j] = fma4s(hj.y, wA1, aA[j]);
                    aB[j] = fma4s(hj.y, wB1, aB[j]);
                }
            }
            float4 bbA = *(const float4*)&bblk[L * HID + c0a];
            float4 bbB = *(const float4*)&bblk[L * HID + c0b];
#pragma unroll
            for (int j = 0; j < MLP_RPB; ++j) {
                aA[j].x += __shfl_xor(aA[j].x, 32, 64);
                aA[j].y += __shfl_xor(aA[j].y, 32, 64);
                aA[j].z += __shfl_xor(aA[j].z, 32, 64);
                aA[j].w += __shfl_xor(aA[j].w, 32, 64);
                aB[j].x += __shfl_xor(aB[j].x, 32, 64);
                aB[j].y += __shfl_xor(aB[j].y, 32, 64);
                aB[j].z += __shfl_xor(aB[j].z, 32, 64);
                aB[j].w += __shfl_xor(aB[j].w, 32, 64);
                float4 h = *(float4*)&hA[j * HID + c0a];
                h.x += fmaxf(aA[j].x + bbA.x, 0.f);
                h.y += fmaxf(aA[j].y + bbA.y, 0.f);
                h.z += fmaxf(aA[j].z + bbA.z, 0.f);
                h.w += fmaxf(aA[j].w + bbA.w, 0.f);
                *(float4*)&hA[j * HID + c0a] = h;
                float4 g = *(float4*)&hA[j * HID + c0b];
                g.x += fmaxf(aB[j].x + bbB.x, 0.f);
                g.y += fmaxf(aB[j].y + bbB.y, 0.f);
                g.z += fmaxf(aB[j].z + bbB.z, 0.f);
                g.w += fmaxf(aB[j].w + bbB.w, 0.f);
                *(float4*)&hA[j * HID + c0b] = g;
            }
        }
        // output layer + sigmoid
        float4 woA = *(const float4*)&Wout[c0a];
        float4 woB = *(const float4*)&Wout[c0b];
        float bo = bout[0];
        float p[MLP_RPB];
#pragma unroll
        for (int j = 0; j < MLP_RPB; ++j) {
            float4 ha = *(const float4*)&hA[j * HID + c0a];
            float4 hb = *(const float4*)&hA[j * HID + c0b];
            p[j] = ha.x * woA.x + ha.y * woA.y + ha.z * woA.z + ha.w * woA.w
                 + hb.x * woB.x + hb.y * woB.y + hb.z * woB.z + hb.w * woB.w;
        }
#pragma unroll
        for (int st = 1; st < 32; st <<= 1)
#pragma unroll
            for (int j = 0; j < MLP_RPB; ++j) p[j] += __shfl_xor(p[j], st, 64);
        if (lane == 0) {
#pragma unroll
            for (int j = 0; j < MLP_RPB; ++j) {
                int gr = row0 + j;
                if (gr < N_MESH) ws_density[gr] = sigmoid_fast(p[j] + bo);
            }
        }
    }
}

// ---------------------------------------------------------------------------
// k2: phase2 serial chain (prefetch all 16 PQ), boundary state into .x slot;
// plus density sum (one extra block).
// ---------------------------------------------------------------------------
__global__ __launch_bounds__(256) void k2_phase2_sum(
    const float* __restrict__ s0_in, float* __restrict__ PQf,
    const float* __restrict__ density, float* __restrict__ sum_out)
{
    const int tid = threadIdx.x;
    if (blockIdx.x == 24) {
        if (blockIdx.y != 0) return;
        __shared__ float red[4];
        float p = 0.f;
        for (int i = tid; i < N_MESH; i += 256) p += density[i];
#pragma unroll
        for (int st = 1; st < 64; st <<= 1) p += __shfl_xor(p, st, 64);
        int lane = tid & 63, w = tid >> 6;
        if (lane == 0) red[w] = p;
        __syncthreads();
        if (tid == 0) sum_out[0] = red[0] + red[1] + red[2] + red[3];
        return;
    }
    const int n = blockIdx.x * 256 + tid;
    const int b = blockIdx.y;
    float2 v[NCHUNK];
    const float2* PQ = (const float2*)PQf;
#pragma unroll
    for (int c = 0; c < NCHUNK; ++c)
        v[c] = PQ[((size_t)(c * NB + b)) * NPAD + n];
    float s = (n < N_MESH) ? s0_in[b * N_MESH + n] : 0.f;
#pragma unroll
    for (int c = 0; c < NCHUNK; ++c) {
        size_t idx = ((size_t)(c * NB + b)) * NPAD + n;
        PQf[2 * idx] = s;                 // boundary state for chunk c
        s = fmaf(v[c].x, s, v[c].y);
    }
}

// ---------------------------------------------------------------------------
// k3: phase3 replay. z-form: z = (z+dl)*A; sign term added in k4.
// ---------------------------------------------------------------------------
__global__ __launch_bounds__(256) void k3_phase3(
    const float* __restrict__ dec, const float* __restrict__ y0,
    const float* __restrict__ mesh, const float* __restrict__ density,
    const float* __restrict__ PQf, float* __restrict__ partials)
{
    __shared__ __align__(16) char smem[SMEM3];
    float* hs2 = (float*)smem;
    float* sgv = (float*)(smem + OFF_SGV);
    unsigned short* tab = (unsigned short*)(smem + OFF_TAB);

    const int tid = threadIdx.x;
    const int bx = blockIdx.x;
    const int nb = bx % NBLK3;
    const int rem = bx / NBLK3;
    const int b = rem & 7;
    const int c = rem >> 3;
    const int t0 = c * CHUNK;
    const int lane = tid & 63, w = tid >> 6;

    if (tid < CHUNK) hs2[tid + 1] = dec[b * TT + t0 + tid];
    if (tid == 0) hs2[0] = (c == 0) ? y0[b] : dec[b * TT + t0 - 1];
    __syncthreads();
    build_table(tid, 256, hs2, sgv, tab);
    __syncthreads();

    int ga[4], gb[4];
    float d[4], z[4];
    float gprev = sgv[0];
#pragma unroll
    for (int q = 0; q < 4; ++q) {
        int n = nb * 1024 + q * 256 + tid;
        float S = 0.f;
        if (n < N_MESH) {
            gb[q] = (int)(mesh[2 * n]     * 100.0f + 0.5f);
            ga[q] = (int)(mesh[2 * n + 1] * 100.0f + 0.5f);
            d[q]  = density[n];
            S = PQf[2 * (((size_t)(c * NB + b)) * NPAD + n)];
        } else { ga[q] = 0; gb[q] = 0; d[q] = 0.f; }
        z[q] = S - gprev;
    }

    float* pout = partials +
        ((size_t)((b * NBLK3 + nb) * 8 + w * 2 + (lane >> 5))) * TT + t0;

    for (int tb = 0; tb < CHUNK; tb += 16) {
        float v[16];
#pragma unroll
        for (int j = 0; j < 16; ++j) {
            int t = tb + j;
            float sgt = sgv[t];
            float dl = gprev - sgt;
            gprev = sgt;
            bool inc = sgt > 0.0f;
            int base = t * TSTR;
            float a0, a1;
#pragma unroll
            for (int q = 0; q < 4; ++q) {
                int ig = inc ? ga[q] : gb[q];
                float A = __half2float(__ushort_as_half(tab[base + ig]));
                z[q] = (z[q] + dl) * A;
            }
            a0 = d[0] * z[0];
            a1 = d[1] * z[1];
            a0 = fmaf(d[2], z[2], a0);
            a1 = fmaf(d[3], z[3], a1);
            v[j] = a0 + a1;
        }
#pragma unroll
        for (int st = 1; st < 32; st <<= 1) {
#pragma unroll
            for (int j = 0; j < 16; ++j) v[j] += __shfl_xor(v[j], st, 64);
        }
        float outv = v[0];
#pragma unroll
        for (int j = 1; j < 16; ++j) if ((lane & 15) == j) outv = v[j];
        if ((lane & 16) == 0) pout[tb + (lane & 15)] = outv;
    }
}

// ---------------------------------------------------------------------------
// k4: outputs. m_t = (sum partials + g_t*D)/D ; plus broadcasts/copies.
// ---------------------------------------------------------------------------
__global__ __launch_bounds__(256) void k4_outputs(
    const float* __restrict__ partials, const float* __restrict__ sum_ptr,
    const float* __restrict__ density, const float* __restrict__ s0,
    const float* __restrict__ mesh, const float* __restrict__ dec,
    const float* __restrict__ y0, float* __restrict__ out)
{
    int i = blockIdx.x * blockDim.x + threadIdx.x;
    const int NM = NB * TT;
    if (i < NM) {
        int b = i >> 11, t = i & (TT - 1);
        float h  = dec[b * TT + t];
        float hp = t ? dec[b * TT + t - 1] : y0[b];
        float g  = (h >= hp) ? 1.0f : -1.0f;
        float acc = 0.f;
#pragma unroll 8
        for (int k = 0; k < NBLK3 * 8; ++k)
            acc += partials[((size_t)(b * NBLK3 * 8 + k)) * TT + t];
        float D = sum_ptr[0];
        float m = (acc + g * D) / D;
        out[OUT_M + i] = m;
        out[OUT_BNORM + i] = 0.5f * m + 0.5f;
        return;
    }
    int j = i - NM;
    const int n1 = NB * N_MESH;
    if (j < n1) {
        out[OUT_DENSB + j] = density[j % N_MESH];
    } else if (j < 2 * n1) {
        int jj = j - n1;
        out[OUT_S0 + jj] = s0[jj];
    } else if (j < 4 * n1) {
        int jj = j - 2 * n1;
        out[OUT_MESHB + jj] = mesh[jj % (2 * N_MESH)];
    }
}

extern "C" void kernel_launch(void* const* d_in, const int* in_sizes, int n_in,
                              void* d_out, int out_size, void* d_ws, size_t ws_size,
                              hipStream_t stream) {
    const float* dec  = (const float*)d_in[1];
    const float* s0   = (const float*)d_in[2];
    const float* y0   = (const float*)d_in[3];
    const float* mesh = (const float*)d_in[4];
    const float* Win  = (const float*)d_in[5];
    const float* bin  = (const float*)d_in[6];
    const float* Wblk = (const float*)d_in[7];
    const float* bblk = (const float*)d_in[8];
    const float* Wout = (const float*)d_in[9];
    const float* bout = (const float*)d_in[10];
    float* out = (float*)d_out;
    float* ws  = (float*)d_ws;

    float* ws_density  = ws + WS_DENSITY;
    float* ws_sum      = ws + WS_SUM;
    float* ws_partials = ws + WS_PART;
    float* ws_pq       = ws + WS_PQ;

    k1_fused<<<K1_GRID, 320, 0, stream>>>(
        dec, y0, mesh, Win, bin, Wblk, bblk, Wout, bout,
        ws_density, (float2*)ws_pq);
    k2_phase2_sum<<<dim3(25, NB), 256, 0, stream>>>(
        s0, ws_pq, ws_density, ws_sum);
    k3_phase3<<<K1_GRID, 256, 0, stream>>>(
        dec, y0, mesh, ws_density, ws_pq, ws_partials);
    {
        int total = NB * TT + NB * N_MESH * 4;   // 181216
        k4_outputs<<<(total + 255) / 256, 256, 0, stream>>>(
            ws_partials, ws_sum, ws_density, s0, mesh, dec, y0, out);
    }
}

// Round 8
// 168.500 us; speedup vs baseline: 1.1205x; 1.1205x over previous
//
#include <hip/hip_runtime.h>
#include <hip/hip_fp16.h>
#include <math.h>

#define N_MESH   5151
#define NB       8
#define TT       2048
#define HID      256
#define NLAYERS  3
#define NCHUNK   16
#define CHUNK    128           // TT / NCHUNK
#define TSTR     104           // sigma table row stride (ushort)
#define NPAD     6144          // 6 blocks * 1024
#define NBLK1    6             // scan n-blocks (1024 pts each, 4/thread)
#define NBLK3    6
#define SCAN_GRID (NBLK1 * NB * NCHUNK)   // 768
#define PREP_NBLK 96           // W fragment-gather blocks (appended to k1)
#define MLP_NBLK  81           // 81*64 = 5184 >= 5151 rows

// scan smem layout (bytes)
#define OFF_SGV   528          // hs2 = 132 floats @0
#define OFF_TAB   1056         // sgv = 128 floats @528
#define SMEMS     27680        // tab = 128*104 ushort = 26624 B

// ws layout (floats)
#define WS_DENSITY 0           // 5151
#define WS_SUM     5184        // 1
#define WS_PART    6144        // NB*NBLK3*8*TT = 786432 -> ends 792576
                               // [WT aliases first 98304 floats: dead before k3]
#define WS_PQ      792576      // NCHUNK*NB*NPAD*2 = 1572864 -> ends 2365440

// out layout (floats)
#define OUT_BNORM  0           // 16384
#define OUT_DENSB  16384       // 41208
#define OUT_M      57592       // 16384
#define OUT_S0     73976       // 41208
#define OUT_MESHB  115184      // 82416

typedef _Float16 half8  __attribute__((ext_vector_type(8)));
typedef _Float16 half4v __attribute__((ext_vector_type(4)));
typedef float    f32x4  __attribute__((ext_vector_type(4)));

__device__ __forceinline__ float sigmoid_fast(float x) {
    float e = __expf(-x);
    return __builtin_amdgcn_rcpf(1.0f + e);
}

// hA byte offset with bank-conflict XOR swizzle (row stride 512 B fp16)
__device__ __forceinline__ int swz(int lr, int kbyte) {
    return lr * 512 + (kbyte ^ ((lr & 7) << 4));
}

// Direction-resolved A-table (fp16), linear conflict-free build.
__device__ __forceinline__ void build_table(int tid, const float* hs2,
                                            float* sgv, unsigned short* tab)
{
    if (tid < CHUNK) sgv[tid] = (hs2[tid + 1] >= hs2[tid]) ? 1.0f : -1.0f;
    for (int idx = tid; idx < CHUNK * TSTR; idx += 256) {
        int t = idx / TSTR;
        int g = idx - t * TSTR;
        float ht = hs2[t + 1];
        bool inc = (ht >= hs2[t]);
        float bx = ht * 1000.0f;
        float y = inc ? fmaf(-10.f, (float)g, bx) : fmaf(10.f, (float)g, -bx);
        float A = __builtin_amdgcn_rcpf(1.0f + __expf(y));
        tab[idx] = __half_as_ushort(__float2half(A));
    }
}

// ---------------------------------------------------------------------------
// k1: blocks [0,768) scan phase1; blocks [768,864) W-fragment gather (prep).
// ---------------------------------------------------------------------------
__global__ __launch_bounds__(256) void k1_scan1_prep(
    const float* __restrict__ dec, const float* __restrict__ y0,
    const float* __restrict__ mesh, const float* __restrict__ Wblk,
    float2* __restrict__ PQ, half8* __restrict__ WT)
{
    __shared__ __align__(16) char smem[SMEMS];
    const int tid = threadIdx.x;

    if (blockIdx.x >= SCAN_GRID) {
        // ---- prep: gather W into per-lane MFMA fragment order ----
        int g = (blockIdx.x - SCAN_GRID) * 256 + tid;   // [0, 24576)
        int l  = g & 63;
        int nt = (g >> 6) & 15;
        int kg = (g >> 10) & 7;
        int L  = g >> 13;
        int n  = nt * 16 + (l & 15);
        int kb = kg * 32 + ((l >> 4) & 3) * 8;
        const float* Wb = Wblk + (size_t)L * HID * HID;
        half8 v;
#pragma unroll
        for (int i = 0; i < 8; ++i)
            v[i] = (_Float16)Wb[(size_t)(kb + i) * HID + n];
        WT[g] = v;
        return;
    }

    // ---- scan phase 1 ----
    float* hs2 = (float*)smem;
    float* sgv = (float*)(smem + OFF_SGV);
    unsigned short* tab = (unsigned short*)(smem + OFF_TAB);

    const int sb = blockIdx.x;
    const int nb = sb % NBLK1;
    const int rem = sb / NBLK1;
    const int b = rem & 7;
    const int c = rem >> 3;
    const int t0 = c * CHUNK;

    if (tid < CHUNK) hs2[tid + 1] = dec[b * TT + t0 + tid];
    if (tid == 0) hs2[0] = (c == 0) ? y0[b] : dec[b * TT + t0 - 1];

    int ga[4], gb[4];
#pragma unroll
    for (int q = 0; q < 4; ++q) {
        int n = nb * 1024 + q * 256 + tid;
        if (n < N_MESH) {
            gb[q] = (int)(mesh[2 * n]     * 100.0f + 0.5f);
            ga[q] = (int)(mesh[2 * n + 1] * 100.0f + 0.5f);
        } else { ga[q] = 0; gb[q] = 0; }
    }
    __syncthreads();
    build_table(tid, hs2, sgv, tab);
    __syncthreads();

    float P[4] = {1.f, 1.f, 1.f, 1.f};
    float R[4];
    float gprev = sgv[0];
#pragma unroll
    for (int q = 0; q < 4; ++q) R[q] = -gprev;

    for (int tb = 0; tb < CHUNK; tb += 16) {
#pragma unroll
        for (int j = 0; j < 16; ++j) {
            int t = tb + j;
            float sgt = sgv[t];
            float dl = gprev - sgt;      // 0 or +-2, wave-uniform
            gprev = sgt;
            bool inc = sgt > 0.0f;
            int base = t * TSTR;
#pragma unroll
            for (int q = 0; q < 4; ++q) {
                int ig = inc ? ga[q] : gb[q];
                float A = __half2float(__ushort_as_half(tab[base + ig]));
                float r = R[q] + dl;
                P[q] *= A;
                R[q] = r * A;
            }
        }
    }
    size_t basew = ((size_t)(c * NB + b)) * NPAD;
#pragma unroll
    for (int q = 0; q < 4; ++q) {
        int n = nb * 1024 + q * 256 + tid;
        float2 v; v.x = P[q]; v.y = R[q] + gprev;
        PQ[basew + n] = v;
    }
}

// ---------------------------------------------------------------------------
// k_mlp: MFMA density MLP. 81 blocks x 4 waves; wave owns 16 rows (no
// barriers). A (h) fp16 in swizzled LDS; B from pre-gathered WT fragments
// (coalesced 16B/lane). D layout: col=lane&15, row=(lane>>4)*4+reg.
// ---------------------------------------------------------------------------
__global__ __launch_bounds__(256) void k_mlp(
    const float* __restrict__ mesh, const float* __restrict__ Win,
    const float* __restrict__ bin,  const half8* __restrict__ WT,
    const float* __restrict__ bblk, const float* __restrict__ Wout,
    const float* __restrict__ bout, float* __restrict__ density)
{
    __shared__ __align__(16) char hA[64 * 512];   // 64 rows x 256 fp16 = 32 KB
    const int tid  = threadIdx.x;
    const int w    = tid >> 6;
    const int lane = tid & 63;
    const int rl   = lane & 15;          // row-in-tile (A) / col (B,D)
    const int cg   = lane >> 4;          // k-group
    const int lr   = w * 16 + rl;        // LDS row for A reads
    const int row0 = blockIdx.x * 64 + w * 16;

    // ---- input layer: h0 = relu(mesh @ Win + bin), fp16 -> hA ----
    {
        int gr = row0 + rl;
        float m0 = 0.f, m1 = 0.f;
        if (gr < N_MESH) { m0 = mesh[2 * gr]; m1 = mesh[2 * gr + 1]; }
        for (int c = cg * 64; c < cg * 64 + 64; c += 4) {
            float4 wa = *(const float4*)&Win[c];
            float4 wb = *(const float4*)&Win[HID + c];
            float4 bi = *(const float4*)&bin[c];
            half4v hv;
            hv[0] = (_Float16)fmaxf(fmaf(m0, wa.x, fmaf(m1, wb.x, bi.x)), 0.f);
            hv[1] = (_Float16)fmaxf(fmaf(m0, wa.y, fmaf(m1, wb.y, bi.y)), 0.f);
            hv[2] = (_Float16)fmaxf(fmaf(m0, wa.z, fmaf(m1, wb.z, bi.z)), 0.f);
            hv[3] = (_Float16)fmaxf(fmaf(m0, wa.w, fmaf(m1, wb.w, bi.w)), 0.f);
            *(half4v*)(hA + swz(lr, c * 2)) = hv;
        }
    }

    // ---- 3 residual layers via MFMA ----
    for (int L = 0; L < NLAYERS; ++L) {
        half8 af[8];
#pragma unroll
        for (int kg = 0; kg < 8; ++kg)
            af[kg] = *(const half8*)(hA + swz(lr, kg * 64 + cg * 16));

        const half8* WTL = WT + (size_t)L * 8 * 16 * 64;
#pragma unroll
        for (int nh = 0; nh < 2; ++nh) {
            f32x4 acc[8];
#pragma unroll
            for (int j = 0; j < 8; ++j) acc[j] = (f32x4){0.f, 0.f, 0.f, 0.f};
#pragma unroll
            for (int kg = 0; kg < 8; ++kg) {
                const half8* Bp = WTL + (size_t)(kg * 16 + nh * 8) * 64 + lane;
#pragma unroll
                for (int j = 0; j < 8; ++j) {
                    half8 bf = Bp[(size_t)j * 64];
                    acc[j] = __builtin_amdgcn_mfma_f32_16x16x32_f16(
                        af[kg], bf, acc[j], 0, 0, 0);
                }
            }
            // epilogue: h += relu(acc + bias)
#pragma unroll
            for (int j = 0; j < 8; ++j) {
                int n = (nh * 8 + j) * 16 + rl;
                float bias = bblk[L * HID + n];
#pragma unroll
                for (int r = 0; r < 4; ++r) {
                    int m = cg * 4 + r;
                    int off = swz(w * 16 + m, n * 2);
                    float old = (float)(*(_Float16*)(hA + off));
                    float nv = old + fmaxf(acc[j][r] + bias, 0.f);
                    *(_Float16*)(hA + off) = (_Float16)nv;
                }
            }
        }
    }

    // ---- output layer + sigmoid ----
    {
        float p = 0.f;
        int kc = cg * 64;
#pragma unroll
        for (int i8 = 0; i8 < 64; i8 += 8) {
            half8 hv = *(const half8*)(hA + swz(lr, (kc + i8) * 2));
            float4 w0 = *(const float4*)&Wout[kc + i8];
            float4 w1 = *(const float4*)&Wout[kc + i8 + 4];
            p += (float)hv[0] * w0.x + (float)hv[1] * w0.y
               + (float)hv[2] * w0.z + (float)hv[3] * w0.w
               + (float)hv[4] * w1.x + (float)hv[5] * w1.y
               + (float)hv[6] * w1.z + (float)hv[7] * w1.w;
        }
        p += __shfl_xor(p, 16, 64);
        p += __shfl_xor(p, 32, 64);
        if (lane < 16) {
            int gr = row0 + lane;
            if (gr < N_MESH) density[gr] = sigmoid_fast(p + bout[0]);
        }
    }
}

// ---------------------------------------------------------------------------
// k2: phase2 serial chain (prefetch all 16 PQ), boundary state into .x slot;
// plus density sum (one extra block).
// ---------------------------------------------------------------------------
__global__ __launch_bounds__(256) void k2_phase2_sum(
    const float* __restrict__ s0_in, float* __restrict__ PQf,
    const float* __restrict__ density, float* __restrict__ sum_out)
{
    const int tid = threadIdx.x;
    if (blockIdx.x == 24) {
        if (blockIdx.y != 0) return;
        __shared__ float red[4];
        float p = 0.f;
        for (int i = tid; i < N_MESH; i += 256) p += density[i];
#pragma unroll
        for (int st = 1; st < 64; st <<= 1) p += __shfl_xor(p, st, 64);
        int lane = tid & 63, w = tid >> 6;
        if (lane == 0) red[w] = p;
        __syncthreads();
        if (tid == 0) sum_out[0] = red[0] + red[1] + red[2] + red[3];
        return;
    }
    const int n = blockIdx.x * 256 + tid;
    const int b = blockIdx.y;
    float2 v[NCHUNK];
    const float2* PQ = (const float2*)PQf;
#pragma unroll
    for (int c = 0; c < NCHUNK; ++c)
        v[c] = PQ[((size_t)(c * NB + b)) * NPAD + n];
    float s = (n < N_MESH) ? s0_in[b * N_MESH + n] : 0.f;
#pragma unroll
    for (int c = 0; c < NCHUNK; ++c) {
        size_t idx = ((size_t)(c * NB + b)) * NPAD + n;
        PQf[2 * idx] = s;                 // boundary state for chunk c
        s = fmaf(v[c].x, s, v[c].y);
    }
}

// ---------------------------------------------------------------------------
// k3: phase3 replay. z-form: z = (z+dl)*A; sign term added in k4.
// ---------------------------------------------------------------------------
__global__ __launch_bounds__(256) void k3_phase3(
    const float* __restrict__ dec, const float* __restrict__ y0,
    const float* __restrict__ mesh, const float* __restrict__ density,
    const float* __restrict__ PQf, float* __restrict__ partials)
{
    __shared__ __align__(16) char smem[SMEMS];
    float* hs2 = (float*)smem;
    float* sgv = (float*)(smem + OFF_SGV);
    unsigned short* tab = (unsigned short*)(smem + OFF_TAB);

    const int tid = threadIdx.x;
    const int bx = blockIdx.x;
    const int nb = bx % NBLK3;
    const int rem = bx / NBLK3;
    const int b = rem & 7;
    const int c = rem >> 3;
    const int t0 = c * CHUNK;
    const int lane = tid & 63, w = tid >> 6;

    if (tid < CHUNK) hs2[tid + 1] = dec[b * TT + t0 + tid];
    if (tid == 0) hs2[0] = (c == 0) ? y0[b] : dec[b * TT + t0 - 1];
    __syncthreads();
    build_table(tid, hs2, sgv, tab);
    __syncthreads();

    int ga[4], gb[4];
    float d[4], z[4];
    float gprev = sgv[0];
#pragma unroll
    for (int q = 0; q < 4; ++q) {
        int n = nb * 1024 + q * 256 + tid;
        float S = 0.f;
        if (n < N_MESH) {
            gb[q] = (int)(mesh[2 * n]     * 100.0f + 0.5f);
            ga[q] = (int)(mesh[2 * n + 1] * 100.0f + 0.5f);
            d[q]  = density[n];
            S = PQf[2 * (((size_t)(c * NB + b)) * NPAD + n)];
        } else { ga[q] = 0; gb[q] = 0; d[q] = 0.f; }
        z[q] = S - gprev;
    }

    float* pout = partials +
        ((size_t)((b * NBLK3 + nb) * 8 + w * 2 + (lane >> 5))) * TT + t0;

    for (int tb = 0; tb < CHUNK; tb += 16) {
        float v[16];
#pragma unroll
        for (int j = 0; j < 16; ++j) {
            int t = tb + j;
            float sgt = sgv[t];
            float dl = gprev - sgt;
            gprev = sgt;
            bool inc = sgt > 0.0f;
            int base = t * TSTR;
            float a0, a1;
#pragma unroll
            for (int q = 0; q < 4; ++q) {
                int ig = inc ? ga[q] : gb[q];
                float A = __half2float(__ushort_as_half(tab[base + ig]));
                z[q] = (z[q] + dl) * A;
            }
            a0 = d[0] * z[0];
            a1 = d[1] * z[1];
            a0 = fmaf(d[2], z[2], a0);
            a1 = fmaf(d[3], z[3], a1);
            v[j] = a0 + a1;
        }
#pragma unroll
        for (int st = 1; st < 32; st <<= 1) {
#pragma unroll
            for (int j = 0; j < 16; ++j) v[j] += __shfl_xor(v[j], st, 64);
        }
        float outv = v[0];
#pragma unroll
        for (int j = 1; j < 16; ++j) if ((lane & 15) == j) outv = v[j];
        if ((lane & 16) == 0) pout[tb + (lane & 15)] = outv;
    }
}

// ---------------------------------------------------------------------------
// k4: outputs. m_t = (sum partials + g_t*D)/D ; plus broadcasts/copies.
// ---------------------------------------------------------------------------
__global__ __launch_bounds__(256) void k4_outputs(
    const float* __restrict__ partials, const float* __restrict__ sum_ptr,
    const float* __restrict__ density, const float* __restrict__ s0,
    const float* __restrict__ mesh, const float* __restrict__ dec,
    const float* __restrict__ y0, float* __restrict__ out)
{
    int i = blockIdx.x * blockDim.x + threadIdx.x;
    const int NM = NB * TT;
    if (i < NM) {
        int b = i >> 11, t = i & (TT - 1);
        float h  = dec[b * TT + t];
        float hp = t ? dec[b * TT + t - 1] : y0[b];
        float g  = (h >= hp) ? 1.0f : -1.0f;
        float acc = 0.f;
#pragma unroll 8
        for (int k = 0; k < NBLK3 * 8; ++k)
            acc += partials[((size_t)(b * NBLK3 * 8 + k)) * TT + t];
        float D = sum_ptr[0];
        float m = (acc + g * D) / D;
        out[OUT_M + i] = m;
        out[OUT_BNORM + i] = 0.5f * m + 0.5f;
        return;
    }
    int j = i - NM;
    const int n1 = NB * N_MESH;
    if (j < n1) {
        out[OUT_DENSB + j] = density[j % N_MESH];
    } else if (j < 2 * n1) {
        int jj = j - n1;
        out[OUT_S0 + jj] = s0[jj];
    } else if (j < 4 * n1) {
        int jj = j - 2 * n1;
        out[OUT_MESHB + jj] = mesh[jj % (2 * N_MESH)];
    }
}

extern "C" void kernel_launch(void* const* d_in, const int* in_sizes, int n_in,
                              void* d_out, int out_size, void* d_ws, size_t ws_size,
                              hipStream_t stream) {
    const float* dec  = (const float*)d_in[1];
    const float* s0   = (const float*)d_in[2];
    const float* y0   = (const float*)d_in[3];
    const float* mesh = (const float*)d_in[4];
    const float* Win  = (const float*)d_in[5];
    const float* bin  = (const float*)d_in[6];
    const float* Wblk = (const float*)d_in[7];
    const float* bblk = (const float*)d_in[8];
    const float* Wout = (const float*)d_in[9];
    const float* bout = (const float*)d_in[10];
    float* out = (float*)d_out;
    float* ws  = (float*)d_ws;

    float* ws_density  = ws + WS_DENSITY;
    float* ws_sum      = ws + WS_SUM;
    float* ws_partials = ws + WS_PART;
    float* ws_pq       = ws + WS_PQ;
    half8* WT          = (half8*)(ws + WS_PART);   // aliases partials (dead by k3)

    k1_scan1_prep<<<SCAN_GRID + PREP_NBLK, 256, 0, stream>>>(
        dec, y0, mesh, Wblk, (float2*)ws_pq, WT);
    k_mlp<<<MLP_NBLK, 256, 0, stream>>>(
        mesh, Win, bin, WT, bblk, Wout, bout, ws_density);
    k2_phase2_sum<<<dim3(25, NB), 256, 0, stream>>>(
        s0, ws_pq, ws_density, ws_sum);
    k3_phase3<<<SCAN_GRID, 256, 0, stream>>>(
        dec, y0, mesh, ws_density, ws_pq, ws_partials);
    {
        int total = NB * TT + NB * N_MESH * 4;   // 181216
        k4_outputs<<<(total + 255) / 256, 256, 0, stream>>>(
            ws_partials, ws_sum, ws_density, s0, mesh, dec, y0, out);
    }
}

// Round 9
// 104.010 us; speedup vs baseline: 1.8153x; 1.6200x over previous
//
#include <hip/hip_runtime.h>
#include <hip/hip_fp16.h>
#include <math.h>

#define N_MESH   5151
#define NB       8
#define TT       2048
#define HID      256
#define NLAYERS  3
#define NCHUNK   16
#define CHUNK    128           // TT / NCHUNK
#define TSTR     104           // sigma table row stride (ushort)
#define NPAD     6144          // 6 blocks * 1024
#define NBLK1    6             // scan n-blocks (1024 pts each, 4/thread)
#define NBLK3    6
#define SCAN_GRID (NBLK1 * NB * NCHUNK)   // 768
#define PREP_NBLK 96           // W fragment-gather blocks (appended to k1)
#define MLP_NBLK  81           // 81*64 = 5184 >= 5151 rows

// scan smem layout (bytes)
#define OFF_SGV   528          // hs2 = 132 floats @0
#define OFF_TAB   1056         // sgv = 128 floats @528
#define SMEMS     27680        // tab = 128*104 ushort = 26624 B

// ws layout (floats)
#define WS_DENSITY 0           // 5151
#define WS_SUM     5184        // 1
#define WS_PART    6144        // NB*NBLK3*8*TT = 786432 -> ends 792576
                               // [WT aliases first 98304 floats: dead before k3]
#define WS_PQ      792576      // NCHUNK*NB*NPAD*2 = 1572864 -> ends 2365440

// out layout (floats)
#define OUT_BNORM  0           // 16384
#define OUT_DENSB  16384       // 41208
#define OUT_M      57592       // 16384
#define OUT_S0     73976       // 41208
#define OUT_MESHB  115184      // 82416

typedef _Float16 half8  __attribute__((ext_vector_type(8)));
typedef float    f32x4  __attribute__((ext_vector_type(4)));

__device__ __forceinline__ float sigmoid_fast(float x) {
    float e = __expf(-x);
    return __builtin_amdgcn_rcpf(1.0f + e);
}

// hA byte offset with bank-conflict XOR swizzle (row stride 512 B fp16)
__device__ __forceinline__ int swz(int row, int kbyte) {
    return row * 512 + (kbyte ^ ((row & 7) << 4));
}

// Direction-resolved A-table (fp16), linear conflict-free build.
__device__ __forceinline__ void build_table(int tid, const float* hs2,
                                            float* sgv, unsigned short* tab)
{
    if (tid < CHUNK) sgv[tid] = (hs2[tid + 1] >= hs2[tid]) ? 1.0f : -1.0f;
    for (int idx = tid; idx < CHUNK * TSTR; idx += 256) {
        int t = idx / TSTR;
        int g = idx - t * TSTR;
        float ht = hs2[t + 1];
        bool inc = (ht >= hs2[t]);
        float bx = ht * 1000.0f;
        float y = inc ? fmaf(-10.f, (float)g, bx) : fmaf(10.f, (float)g, -bx);
        float A = __builtin_amdgcn_rcpf(1.0f + __expf(y));
        tab[idx] = __half_as_ushort(__float2half(A));
    }
}

// ---------------------------------------------------------------------------
// k1: blocks [0,768) scan phase1; blocks [768,864) W-fragment gather (prep).
// ---------------------------------------------------------------------------
__global__ __launch_bounds__(256) void k1_scan1_prep(
    const float* __restrict__ dec, const float* __restrict__ y0,
    const float* __restrict__ mesh, const float* __restrict__ Wblk,
    float2* __restrict__ PQ, half8* __restrict__ WT)
{
    __shared__ __align__(16) char smem[SMEMS];
    const int tid = threadIdx.x;

    if (blockIdx.x >= SCAN_GRID) {
        // ---- prep: gather W into per-lane MFMA fragment order ----
        int g = (blockIdx.x - SCAN_GRID) * 256 + tid;   // [0, 24576)
        int l  = g & 63;
        int nt = (g >> 6) & 15;
        int kg = (g >> 10) & 7;
        int L  = g >> 13;
        int n  = nt * 16 + (l & 15);
        int kb = kg * 32 + ((l >> 4) & 3) * 8;
        const float* Wb = Wblk + (size_t)L * HID * HID;
        half8 v;
#pragma unroll
        for (int i = 0; i < 8; ++i)
            v[i] = (_Float16)Wb[(size_t)(kb + i) * HID + n];
        WT[g] = v;
        return;
    }

    // ---- scan phase 1 ----
    float* hs2 = (float*)smem;
    float* sgv = (float*)(smem + OFF_SGV);
    unsigned short* tab = (unsigned short*)(smem + OFF_TAB);

    const int sb = blockIdx.x;
    const int nb = sb % NBLK1;
    const int rem = sb / NBLK1;
    const int b = rem & 7;
    const int c = rem >> 3;
    const int t0 = c * CHUNK;

    if (tid < CHUNK) hs2[tid + 1] = dec[b * TT + t0 + tid];
    if (tid == 0) hs2[0] = (c == 0) ? y0[b] : dec[b * TT + t0 - 1];

    int ga[4], gb[4];
#pragma unroll
    for (int q = 0; q < 4; ++q) {
        int n = nb * 1024 + q * 256 + tid;
        if (n < N_MESH) {
            gb[q] = (int)(mesh[2 * n]     * 100.0f + 0.5f);
            ga[q] = (int)(mesh[2 * n + 1] * 100.0f + 0.5f);
        } else { ga[q] = 0; gb[q] = 0; }
    }
    __syncthreads();
    build_table(tid, hs2, sgv, tab);
    __syncthreads();

    float P[4] = {1.f, 1.f, 1.f, 1.f};
    float R[4];
    float gprev = sgv[0];
#pragma unroll
    for (int q = 0; q < 4; ++q) R[q] = -gprev;

    for (int tb = 0; tb < CHUNK; tb += 16) {
#pragma unroll
        for (int j = 0; j < 16; ++j) {
            int t = tb + j;
            float sgt = sgv[t];
            float dl = gprev - sgt;      // 0 or +-2, wave-uniform
            gprev = sgt;
            bool inc = sgt > 0.0f;
            int base = t * TSTR;
#pragma unroll
            for (int q = 0; q < 4; ++q) {
                int ig = inc ? ga[q] : gb[q];
                float A = __half2float(__ushort_as_half(tab[base + ig]));
                float r = R[q] + dl;
                P[q] *= A;
                R[q] = r * A;
            }
        }
    }
    size_t basew = ((size_t)(c * NB + b)) * NPAD;
#pragma unroll
    for (int q = 0; q < 4; ++q) {
        int n = nb * 1024 + q * 256 + tid;
        float2 v; v.x = P[q]; v.y = R[q] + gprev;
        PQ[basew + n] = v;
    }
}

// ---------------------------------------------------------------------------
// k_mlp v2: 81 blocks x 512 threads (8 waves). Wave = (mt = w&3 row-tile,
// nh = w>>2 col-half). h carried in registers (hreg, D-layout); hA LDS is
// the fp16 cross-wave A-exchange only (writes, no RMW). B fragments from WT
// with explicit 2-deep double-buffer prefetch.
// ---------------------------------------------------------------------------
__global__ __launch_bounds__(512) void k_mlp(
    const float* __restrict__ mesh, const float* __restrict__ Win,
    const float* __restrict__ bin,  const half8* __restrict__ WT,
    const float* __restrict__ bblk, const float* __restrict__ Wout,
    const float* __restrict__ bout, float* __restrict__ density)
{
    __shared__ __align__(16) char hA[64 * 512];   // 64 rows x 256 fp16 = 32 KB
    __shared__ float psum[4][16][2];
    const int tid  = threadIdx.x;
    const int w    = tid >> 6;
    const int lane = tid & 63;
    const int rl   = lane & 15;
    const int cg   = lane >> 4;
    const int mt   = w & 3;
    const int nh   = w >> 2;
    const int row0 = blockIdx.x * 64;

    float hreg[8][4];   // hreg[j][r] = h[row0+mt*16+cg*4+r][nh*128+j*16+rl]

    // ---- input layer ----
    {
        float m0[4], m1[4];
#pragma unroll
        for (int r = 0; r < 4; ++r) {
            int gr = row0 + mt * 16 + cg * 4 + r;
            if (gr < N_MESH) { m0[r] = mesh[2 * gr]; m1[r] = mesh[2 * gr + 1]; }
            else { m0[r] = 0.f; m1[r] = 0.f; }
        }
#pragma unroll
        for (int j = 0; j < 8; ++j) {
            int col = nh * 128 + j * 16 + rl;
            float wa = Win[col], wb = Win[HID + col], bi = bin[col];
#pragma unroll
            for (int r = 0; r < 4; ++r) {
                float v = fmaxf(fmaf(m0[r], wa, fmaf(m1[r], wb, bi)), 0.f);
                hreg[j][r] = v;
                *(_Float16*)(hA + swz(mt * 16 + cg * 4 + r, col * 2)) =
                    (_Float16)v;
            }
        }
    }
    __syncthreads();

    // ---- 3 residual layers ----
    for (int L = 0; L < NLAYERS; ++L) {
        // A fragments: row mt*16+rl, k = kg*32 + cg*8 .. +8
        half8 af[8];
#pragma unroll
        for (int kg = 0; kg < 8; ++kg)
            af[kg] = *(const half8*)(hA + swz(mt * 16 + rl, kg * 64 + cg * 16));
        __syncthreads();   // all af reads done before any hA writes below

        float bias[8];
#pragma unroll
        for (int j = 0; j < 8; ++j)
            bias[j] = bblk[L * HID + nh * 128 + j * 16 + rl];

        f32x4 acc[8];
#pragma unroll
        for (int j = 0; j < 8; ++j) acc[j] = (f32x4){0.f, 0.f, 0.f, 0.f};

        // B stream: frag(kg,j) at WT[((L*8+kg)*16 + nh*8 + j)*64 + lane]
        const half8* WTL = WT + ((size_t)(L * 8) * 16 + nh * 8) * 64 + lane;
        half8 b0[8], b1[8];
#pragma unroll
        for (int j = 0; j < 8; ++j) b0[j] = WTL[(size_t)j * 64];
#pragma unroll
        for (int kg2 = 0; kg2 < 8; kg2 += 2) {
#pragma unroll
            for (int j = 0; j < 8; ++j)
                b1[j] = WTL[(size_t)(kg2 + 1) * 1024 + (size_t)j * 64];
#pragma unroll
            for (int j = 0; j < 8; ++j)
                acc[j] = __builtin_amdgcn_mfma_f32_16x16x32_f16(
                    af[kg2], b0[j], acc[j], 0, 0, 0);
            if (kg2 + 2 < 8) {
#pragma unroll
                for (int j = 0; j < 8; ++j)
                    b0[j] = WTL[(size_t)(kg2 + 2) * 1024 + (size_t)j * 64];
            }
#pragma unroll
            for (int j = 0; j < 8; ++j)
                acc[j] = __builtin_amdgcn_mfma_f32_16x16x32_f16(
                    af[kg2 + 1], b1[j], acc[j], 0, 0, 0);
        }

        // epilogue: hreg += relu(acc + bias); write fp16 h to hA (if needed)
#pragma unroll
        for (int j = 0; j < 8; ++j) {
            int col = nh * 128 + j * 16 + rl;
#pragma unroll
            for (int r = 0; r < 4; ++r) {
                float v = hreg[j][r] + fmaxf(acc[j][r] + bias[j], 0.f);
                hreg[j][r] = v;
                if (L < NLAYERS - 1)
                    *(_Float16*)(hA + swz(mt * 16 + cg * 4 + r, col * 2)) =
                        (_Float16)v;
            }
        }
        if (L < NLAYERS - 1) __syncthreads();
    }

    // ---- output layer: p_row = sum_col h*Wout ----
    {
        float p[4] = {0.f, 0.f, 0.f, 0.f};
#pragma unroll
        for (int j = 0; j < 8; ++j) {
            float wo = Wout[nh * 128 + j * 16 + rl];
#pragma unroll
            for (int r = 0; r < 4; ++r) p[r] = fmaf(hreg[j][r], wo, p[r]);
        }
#pragma unroll
        for (int st = 1; st < 16; st <<= 1)
#pragma unroll
            for (int r = 0; r < 4; ++r) p[r] += __shfl_xor(p[r], st, 64);
        if (rl == 0) {
#pragma unroll
            for (int r = 0; r < 4; ++r) psum[mt][cg * 4 + r][nh] = p[r];
        }
    }
    __syncthreads();
    if (tid < 64) {
        int gr = row0 + tid;
        float pp = psum[tid >> 4][tid & 15][0] + psum[tid >> 4][tid & 15][1];
        if (gr < N_MESH) density[gr] = sigmoid_fast(pp + bout[0]);
    }
}

// ---------------------------------------------------------------------------
// k2: phase2 serial chain (prefetch all 16 PQ), boundary state into .x slot;
// plus density sum (one extra block).
// ---------------------------------------------------------------------------
__global__ __launch_bounds__(256) void k2_phase2_sum(
    const float* __restrict__ s0_in, float* __restrict__ PQf,
    const float* __restrict__ density, float* __restrict__ sum_out)
{
    const int tid = threadIdx.x;
    if (blockIdx.x == 24) {
        if (blockIdx.y != 0) return;
        __shared__ float red[4];
        float p = 0.f;
        for (int i = tid; i < N_MESH; i += 256) p += density[i];
#pragma unroll
        for (int st = 1; st < 64; st <<= 1) p += __shfl_xor(p, st, 64);
        int lane = tid & 63, w = tid >> 6;
        if (lane == 0) red[w] = p;
        __syncthreads();
        if (tid == 0) sum_out[0] = red[0] + red[1] + red[2] + red[3];
        return;
    }
    const int n = blockIdx.x * 256 + tid;
    const int b = blockIdx.y;
    float2 v[NCHUNK];
    const float2* PQ = (const float2*)PQf;
#pragma unroll
    for (int c = 0; c < NCHUNK; ++c)
        v[c] = PQ[((size_t)(c * NB + b)) * NPAD + n];
    float s = (n < N_MESH) ? s0_in[b * N_MESH + n] : 0.f;
#pragma unroll
    for (int c = 0; c < NCHUNK; ++c) {
        size_t idx = ((size_t)(c * NB + b)) * NPAD + n;
        PQf[2 * idx] = s;                 // boundary state for chunk c
        s = fmaf(v[c].x, s, v[c].y);
    }
}

// ---------------------------------------------------------------------------
// k3: phase3 replay. z-form: z = (z+dl)*A; sign term added in k4.
// ---------------------------------------------------------------------------
__global__ __launch_bounds__(256) void k3_phase3(
    const float* __restrict__ dec, const float* __restrict__ y0,
    const float* __restrict__ mesh, const float* __restrict__ density,
    const float* __restrict__ PQf, float* __restrict__ partials)
{
    __shared__ __align__(16) char smem[SMEMS];
    float* hs2 = (float*)smem;
    float* sgv = (float*)(smem + OFF_SGV);
    unsigned short* tab = (unsigned short*)(smem + OFF_TAB);

    const int tid = threadIdx.x;
    const int bx = blockIdx.x;
    const int nb = bx % NBLK3;
    const int rem = bx / NBLK3;
    const int b = rem & 7;
    const int c = rem >> 3;
    const int t0 = c * CHUNK;
    const int lane = tid & 63, w = tid >> 6;

    if (tid < CHUNK) hs2[tid + 1] = dec[b * TT + t0 + tid];
    if (tid == 0) hs2[0] = (c == 0) ? y0[b] : dec[b * TT + t0 - 1];
    __syncthreads();
    build_table(tid, hs2, sgv, tab);
    __syncthreads();

    int ga[4], gb[4];
    float d[4], z[4];
    float gprev = sgv[0];
#pragma unroll
    for (int q = 0; q < 4; ++q) {
        int n = nb * 1024 + q * 256 + tid;
        float S = 0.f;
        if (n < N_MESH) {
            gb[q] = (int)(mesh[2 * n]     * 100.0f + 0.5f);
            ga[q] = (int)(mesh[2 * n + 1] * 100.0f + 0.5f);
            d[q]  = density[n];
            S = PQf[2 * (((size_t)(c * NB + b)) * NPAD + n)];
        } else { ga[q] = 0; gb[q] = 0; d[q] = 0.f; }
        z[q] = S - gprev;
    }

    float* pout = partials +
        ((size_t)((b * NBLK3 + nb) * 8 + w * 2 + (lane >> 5))) * TT + t0;

    for (int tb = 0; tb < CHUNK; tb += 16) {
        float v[16];
#pragma unroll
        for (int j = 0; j < 16; ++j) {
            int t = tb + j;
            float sgt = sgv[t];
            float dl = gprev - sgt;
            gprev = sgt;
            bool inc = sgt > 0.0f;
            int base = t * TSTR;
            float a0, a1;
#pragma unroll
            for (int q = 0; q < 4; ++q) {
                int ig = inc ? ga[q] : gb[q];
                float A = __half2float(__ushort_as_half(tab[base + ig]));
                z[q] = (z[q] + dl) * A;
            }
            a0 = d[0] * z[0];
            a1 = d[1] * z[1];
            a0 = fmaf(d[2], z[2], a0);
            a1 = fmaf(d[3], z[3], a1);
            v[j] = a0 + a1;
        }
#pragma unroll
        for (int st = 1; st < 32; st <<= 1) {
#pragma unroll
            for (int j = 0; j < 16; ++j) v[j] += __shfl_xor(v[j], st, 64);
        }
        float outv = v[0];
#pragma unroll
        for (int j = 1; j < 16; ++j) if ((lane & 15) == j) outv = v[j];
        if ((lane & 16) == 0) pout[tb + (lane & 15)] = outv;
    }
}

// ---------------------------------------------------------------------------
// k4: outputs. m_t = (sum partials + g_t*D)/D ; plus broadcasts/copies.
// ---------------------------------------------------------------------------
__global__ __launch_bounds__(256) void k4_outputs(
    const float* __restrict__ partials, const float* __restrict__ sum_ptr,
    const float* __restrict__ density, const float* __restrict__ s0,
    const float* __restrict__ mesh, const float* __restrict__ dec,
    const float* __restrict__ y0, float* __restrict__ out)
{
    int i = blockIdx.x * blockDim.x + threadIdx.x;
    const int NM = NB * TT;
    if (i < NM) {
        int b = i >> 11, t = i & (TT - 1);
        float h  = dec[b * TT + t];
        float hp = t ? dec[b * TT + t - 1] : y0[b];
        float g  = (h >= hp) ? 1.0f : -1.0f;
        float acc = 0.f;
#pragma unroll 8
        for (int k = 0; k < NBLK3 * 8; ++k)
            acc += partials[((size_t)(b * NBLK3 * 8 + k)) * TT + t];
        float D = sum_ptr[0];
        float m = (acc + g * D) / D;
        out[OUT_M + i] = m;
        out[OUT_BNORM + i] = 0.5f * m + 0.5f;
        return;
    }
    int j = i - NM;
    const int n1 = NB * N_MESH;
    if (j < n1) {
        out[OUT_DENSB + j] = density[j % N_MESH];
    } else if (j < 2 * n1) {
        int jj = j - n1;
        out[OUT_S0 + jj] = s0[jj];
    } else if (j < 4 * n1) {
        int jj = j - 2 * n1;
        out[OUT_MESHB + jj] = mesh[jj % (2 * N_MESH)];
    }
}

extern "C" void kernel_launch(void* const* d_in, const int* in_sizes, int n_in,
                              void* d_out, int out_size, void* d_ws, size_t ws_size,
                              hipStream_t stream) {
    const float* dec  = (const float*)d_in[1];
    const float* s0   = (const float*)d_in[2];
    const float* y0   = (const float*)d_in[3];
    const float* mesh = (const float*)d_in[4];
    const float* Win  = (const float*)d_in[5];
    const float* bin  = (const float*)d_in[6];
    const float* Wblk = (const float*)d_in[7];
    const float* bblk = (const float*)d_in[8];
    const float* Wout = (const float*)d_in[9];
    const float* bout = (const float*)d_in[10];
    float* out = (float*)d_out;
    float* ws  = (float*)d_ws;

    float* ws_density  = ws + WS_DENSITY;
    float* ws_sum      = ws + WS_SUM;
    float* ws_partials = ws + WS_PART;
    float* ws_pq       = ws + WS_PQ;
    half8* WT          = (half8*)(ws + WS_PART);   // aliases partials (dead by k3)

    k1_scan1_prep<<<SCAN_GRID + PREP_NBLK, 256, 0, stream>>>(
        dec, y0, mesh, Wblk, (float2*)ws_pq, WT);
    k_mlp<<<MLP_NBLK, 512, 0, stream>>>(
        mesh, Win, bin, WT, bblk, Wout, bout, ws_density);
    k2_phase2_sum<<<dim3(25, NB), 256, 0, stream>>>(
        s0, ws_pq, ws_density, ws_sum);
    k3_phase3<<<SCAN_GRID, 256, 0, stream>>>(
        dec, y0, mesh, ws_density, ws_pq, ws_partials);
    {
        int total = NB * TT + NB * N_MESH * 4;   // 181216
        k4_outputs<<<(total + 255) / 256, 256, 0, stream>>>(
            ws_partials, ws_sum, ws_density, s0, mesh, dec, y0, out);
    }
}

// Round 10
// 88.525 us; speedup vs baseline: 2.1328x; 1.1749x over previous
//
#include <hip/hip_runtime.h>
#include <hip/hip_fp16.h>
#include <math.h>

#define N_MESH   5151
#define NB       8
#define TT       2048
#define HID      256
#define NLAYERS  3
#define NCHUNK   16
#define CHUNK    128           // TT / NCHUNK
#define NG       101           // threshold grid values 0..100
#define TROW     136           // tab row stride in ushorts (272B: 16B-aligned, bank-optimal)
#define NPAD     6144          // 6 blocks * 1024
#define NBLK1    6             // scan n-blocks (1024 pts each, 4/thread)
#define NBLK3    6
#define SCAN_GRID (NBLK1 * NB * NCHUNK)   // 768
#define PREP_NBLK 96           // W fragment-gather blocks (appended to k1)
#define MLP_NBLK  81           // 81*64 = 5184 >= 5151 rows

// scan smem layout (bytes): hs2 @0 (528), sgv @528 (512), tab @1040 (27472)
#define OFF_SGV   528
#define OFF_TAB   1040
#define OFF_RED   28512        // k3 only: 4 waves x 64 floats = 1024
#define SMEM1     28512
#define SMEM3     29536

// ws layout (floats)
#define WS_DENSITY 0           // 5151
#define WS_SUM     5184        // 1
#define WS_PART    6144        // NB*NBLK3*4*TT = 393216 -> ends 399360
                               // [WT aliases first 98304 floats: dead before k3]
#define WS_PQ      399360      // NCHUNK*NB*NPAD*2 = 1572864 -> ends 1972224 (7.9MB)

// out layout (floats)
#define OUT_BNORM  0           // 16384
#define OUT_DENSB  16384       // 41208
#define OUT_M      57592       // 16384
#define OUT_S0     73976       // 41208
#define OUT_MESHB  115184      // 82416

typedef _Float16 half8  __attribute__((ext_vector_type(8)));
typedef unsigned short u16x8 __attribute__((ext_vector_type(8)));
typedef float    f32x4  __attribute__((ext_vector_type(4)));

__device__ __forceinline__ float sigmoid_fast(float x) {
    float e = __expf(-x);
    return __builtin_amdgcn_rcpf(1.0f + e);
}

// hA byte offset with bank-conflict XOR swizzle (row stride 512 B fp16)
__device__ __forceinline__ int swz(int row, int kbyte) {
    return row * 512 + (kbyte ^ ((row & 7) << 4));
}

// 16-lane sum via DPP (VALU pipe, zero DS ops)
__device__ __forceinline__ float dpp16_sum(float v) {
    int a;
    a = __builtin_amdgcn_update_dpp(0, __float_as_int(v), 0xB1, 0xF, 0xF, true);
    v += __int_as_float(a);   // xor1 (quad_perm 1,0,3,2)
    a = __builtin_amdgcn_update_dpp(0, __float_as_int(v), 0x4E, 0xF, 0xF, true);
    v += __int_as_float(a);   // xor2 (quad_perm 2,3,0,1)
    a = __builtin_amdgcn_update_dpp(0, __float_as_int(v), 0x141, 0xF, 0xF, true);
    v += __int_as_float(a);   // row_half_mirror (pairs across 4-boundary)
    a = __builtin_amdgcn_update_dpp(0, __float_as_int(v), 0x140, 0xF, 0xF, true);
    v += __int_as_float(a);   // row_mirror (pairs across 8-boundary)
    return v;
}

// Direction-resolved A-table, [g][t] layout (fp16), conflict-free build.
// inc(t): A = 1/(1+exp(1000h-10g)); dec(t): A = 1/(1+exp(10g-1000h))
__device__ __forceinline__ void build_table(int tid, const float* hs2,
                                            float* sgv, unsigned short* tab)
{
    if (tid < CHUNK) sgv[tid] = (hs2[tid + 1] >= hs2[tid]) ? 1.0f : -1.0f;
    for (int idx = tid; idx < NG * CHUNK; idx += 256) {
        int g = idx >> 7;          // CHUNK = 128
        int t = idx & 127;
        float ht = hs2[t + 1];
        bool inc = (ht >= hs2[t]);
        float bx = ht * 1000.0f;
        float y = inc ? fmaf(-10.f, (float)g, bx) : fmaf(10.f, (float)g, -bx);
        float A = __builtin_amdgcn_rcpf(1.0f + __expf(y));
        tab[g * TROW + t] = __half_as_ushort(__float2half(A));
    }
}

// ---------------------------------------------------------------------------
// k1: blocks [0,768) scan phase1; blocks [768,864) W-fragment gather (prep).
// ---------------------------------------------------------------------------
__global__ __launch_bounds__(256) void k1_scan1_prep(
    const float* __restrict__ dec, const float* __restrict__ y0,
    const float* __restrict__ mesh, const float* __restrict__ Wblk,
    float2* __restrict__ PQ, half8* __restrict__ WT)
{
    __shared__ __align__(16) char smem[SMEM1];
    const int tid = threadIdx.x;

    if (blockIdx.x >= SCAN_GRID) {
        // ---- prep: gather W into per-lane MFMA fragment order ----
        int g = (blockIdx.x - SCAN_GRID) * 256 + tid;   // [0, 24576)
        int l  = g & 63;
        int nt = (g >> 6) & 15;
        int kg = (g >> 10) & 7;
        int L  = g >> 13;
        int n  = nt * 16 + (l & 15);
        int kb = kg * 32 + ((l >> 4) & 3) * 8;
        const float* Wb = Wblk + (size_t)L * HID * HID;
        half8 v;
#pragma unroll
        for (int i = 0; i < 8; ++i)
            v[i] = (_Float16)Wb[(size_t)(kb + i) * HID + n];
        WT[g] = v;
        return;
    }

    float* hs2 = (float*)smem;
    float* sgv = (float*)(smem + OFF_SGV);
    unsigned short* tab = (unsigned short*)(smem + OFF_TAB);

    const int sb = blockIdx.x;
    const int nb = sb % NBLK1;
    const int rem = sb / NBLK1;
    const int b = rem & 7;
    const int c = rem >> 3;
    const int t0 = c * CHUNK;

    if (tid < CHUNK) hs2[tid + 1] = dec[b * TT + t0 + tid];
    if (tid == 0) hs2[0] = (c == 0) ? y0[b] : dec[b * TT + t0 - 1];

    int ga[4], gb[4];
#pragma unroll
    for (int q = 0; q < 4; ++q) {
        int n = nb * 1024 + q * 256 + tid;
        if (n < N_MESH) {
            gb[q] = (int)(mesh[2 * n]     * 100.0f + 0.5f);
            ga[q] = (int)(mesh[2 * n + 1] * 100.0f + 0.5f);
        } else { ga[q] = 0; gb[q] = 0; }
    }
    __syncthreads();
    build_table(tid, hs2, sgv, tab);
    __syncthreads();

    float P[4] = {1.f, 1.f, 1.f, 1.f};
    float R[4];
    float gprev = sgv[0];
#pragma unroll
    for (int q = 0; q < 4; ++q) R[q] = -gprev;

    for (int tb = 0; tb < CHUNK; tb += 8) {
        u16x8 ra[4], rb[4];
#pragma unroll
        for (int q = 0; q < 4; ++q) {
            ra[q] = *(const u16x8*)&tab[ga[q] * TROW + tb];
            rb[q] = *(const u16x8*)&tab[gb[q] * TROW + tb];
        }
        float4 sA = *(const float4*)&sgv[tb];
        float4 sB = *(const float4*)&sgv[tb + 4];
        float sg8[8] = {sA.x, sA.y, sA.z, sA.w, sB.x, sB.y, sB.z, sB.w};
#pragma unroll
        for (int j = 0; j < 8; ++j) {
            float sgt = sg8[j];
            float dl = gprev - sgt;      // 0 or +-2, wave-uniform
            gprev = sgt;
            bool inc = sgt > 0.0f;
#pragma unroll
            for (int q = 0; q < 4; ++q) {
                unsigned short u = inc ? ra[q][j] : rb[q][j];
                float A = __half2float(__ushort_as_half(u));
                float r = R[q] + dl;
                P[q] *= A;
                R[q] = r * A;
            }
        }
    }
    size_t basew = ((size_t)(c * NB + b)) * NPAD;
#pragma unroll
    for (int q = 0; q < 4; ++q) {
        int n = nb * 1024 + q * 256 + tid;
        float2 v; v.x = P[q]; v.y = R[q] + gprev;
        PQ[basew + n] = v;
    }
}

// ---------------------------------------------------------------------------
// k_mlp: MFMA density MLP (proven in R9). 81 blocks x 512 threads.
// ---------------------------------------------------------------------------
__global__ __launch_bounds__(512) void k_mlp(
    const float* __restrict__ mesh, const float* __restrict__ Win,
    const float* __restrict__ bin,  const half8* __restrict__ WT,
    const float* __restrict__ bblk, const float* __restrict__ Wout,
    const float* __restrict__ bout, float* __restrict__ density)
{
    __shared__ __align__(16) char hA[64 * 512];   // 64 rows x 256 fp16 = 32 KB
    __shared__ float psum[4][16][2];
    const int tid  = threadIdx.x;
    const int w    = tid >> 6;
    const int lane = tid & 63;
    const int rl   = lane & 15;
    const int cg   = lane >> 4;
    const int mt   = w & 3;
    const int nh   = w >> 2;
    const int row0 = blockIdx.x * 64;

    float hreg[8][4];

    {
        float m0[4], m1[4];
#pragma unroll
        for (int r = 0; r < 4; ++r) {
            int gr = row0 + mt * 16 + cg * 4 + r;
            if (gr < N_MESH) { m0[r] = mesh[2 * gr]; m1[r] = mesh[2 * gr + 1]; }
            else { m0[r] = 0.f; m1[r] = 0.f; }
        }
#pragma unroll
        for (int j = 0; j < 8; ++j) {
            int col = nh * 128 + j * 16 + rl;
            float wa = Win[col], wb = Win[HID + col], bi = bin[col];
#pragma unroll
            for (int r = 0; r < 4; ++r) {
                float v = fmaxf(fmaf(m0[r], wa, fmaf(m1[r], wb, bi)), 0.f);
                hreg[j][r] = v;
                *(_Float16*)(hA + swz(mt * 16 + cg * 4 + r, col * 2)) =
                    (_Float16)v;
            }
        }
    }
    __syncthreads();

    for (int L = 0; L < NLAYERS; ++L) {
        half8 af[8];
#pragma unroll
        for (int kg = 0; kg < 8; ++kg)
            af[kg] = *(const half8*)(hA + swz(mt * 16 + rl, kg * 64 + cg * 16));
        __syncthreads();

        float bias[8];
#pragma unroll
        for (int j = 0; j < 8; ++j)
            bias[j] = bblk[L * HID + nh * 128 + j * 16 + rl];

        f32x4 acc[8];
#pragma unroll
        for (int j = 0; j < 8; ++j) acc[j] = (f32x4){0.f, 0.f, 0.f, 0.f};

        const half8* WTL = WT + ((size_t)(L * 8) * 16 + nh * 8) * 64 + lane;
        half8 b0[8], b1[8];
#pragma unroll
        for (int j = 0; j < 8; ++j) b0[j] = WTL[(size_t)j * 64];
#pragma unroll
        for (int kg2 = 0; kg2 < 8; kg2 += 2) {
#pragma unroll
            for (int j = 0; j < 8; ++j)
                b1[j] = WTL[(size_t)(kg2 + 1) * 1024 + (size_t)j * 64];
#pragma unroll
            for (int j = 0; j < 8; ++j)
                acc[j] = __builtin_amdgcn_mfma_f32_16x16x32_f16(
                    af[kg2], b0[j], acc[j], 0, 0, 0);
            if (kg2 + 2 < 8) {
#pragma unroll
                for (int j = 0; j < 8; ++j)
                    b0[j] = WTL[(size_t)(kg2 + 2) * 1024 + (size_t)j * 64];
            }
#pragma unroll
            for (int j = 0; j < 8; ++j)
                acc[j] = __builtin_amdgcn_mfma_f32_16x16x32_f16(
                    af[kg2 + 1], b1[j], acc[j], 0, 0, 0);
        }

#pragma unroll
        for (int j = 0; j < 8; ++j) {
            int col = nh * 128 + j * 16 + rl;
#pragma unroll
            for (int r = 0; r < 4; ++r) {
                float v = hreg[j][r] + fmaxf(acc[j][r] + bias[j], 0.f);
                hreg[j][r] = v;
                if (L < NLAYERS - 1)
                    *(_Float16*)(hA + swz(mt * 16 + cg * 4 + r, col * 2)) =
                        (_Float16)v;
            }
        }
        if (L < NLAYERS - 1) __syncthreads();
    }

    {
        float p[4] = {0.f, 0.f, 0.f, 0.f};
#pragma unroll
        for (int j = 0; j < 8; ++j) {
            float wo = Wout[nh * 128 + j * 16 + rl];
#pragma unroll
            for (int r = 0; r < 4; ++r) p[r] = fmaf(hreg[j][r], wo, p[r]);
        }
#pragma unroll
        for (int st = 1; st < 16; st <<= 1)
#pragma unroll
            for (int r = 0; r < 4; ++r) p[r] += __shfl_xor(p[r], st, 64);
        if (rl == 0) {
#pragma unroll
            for (int r = 0; r < 4; ++r) psum[mt][cg * 4 + r][nh] = p[r];
        }
    }
    __syncthreads();
    if (tid < 64) {
        int gr = row0 + tid;
        float pp = psum[tid >> 4][tid & 15][0] + psum[tid >> 4][tid & 15][1];
        if (gr < N_MESH) density[gr] = sigmoid_fast(pp + bout[0]);
    }
}

// ---------------------------------------------------------------------------
// k2: phase2 serial chain + density sum.
// ---------------------------------------------------------------------------
__global__ __launch_bounds__(256) void k2_phase2_sum(
    const float* __restrict__ s0_in, float* __restrict__ PQf,
    const float* __restrict__ density, float* __restrict__ sum_out)
{
    const int tid = threadIdx.x;
    if (blockIdx.x == 24) {
        if (blockIdx.y != 0) return;
        __shared__ float red[4];
        float p = 0.f;
        for (int i = tid; i < N_MESH; i += 256) p += density[i];
#pragma unroll
        for (int st = 1; st < 64; st <<= 1) p += __shfl_xor(p, st, 64);
        int lane = tid & 63, w = tid >> 6;
        if (lane == 0) red[w] = p;
        __syncthreads();
        if (tid == 0) sum_out[0] = red[0] + red[1] + red[2] + red[3];
        return;
    }
    const int n = blockIdx.x * 256 + tid;
    const int b = blockIdx.y;
    float2 v[NCHUNK];
    const float2* PQ = (const float2*)PQf;
#pragma unroll
    for (int c = 0; c < NCHUNK; ++c)
        v[c] = PQ[((size_t)(c * NB + b)) * NPAD + n];
    float s = (n < N_MESH) ? s0_in[b * N_MESH + n] : 0.f;
#pragma unroll
    for (int c = 0; c < NCHUNK; ++c) {
        size_t idx = ((size_t)(c * NB + b)) * NPAD + n;
        PQf[2 * idx] = s;                 // boundary state for chunk c
        s = fmaf(v[c].x, s, v[c].y);
    }
}

// ---------------------------------------------------------------------------
// k3: phase3 replay. Batched b128 table reads + DPP reduction.
// ---------------------------------------------------------------------------
__global__ __launch_bounds__(256) void k3_phase3(
    const float* __restrict__ dec, const float* __restrict__ y0,
    const float* __restrict__ mesh, const float* __restrict__ density,
    const float* __restrict__ PQf, float* __restrict__ partials)
{
    __shared__ __align__(16) char smem[SMEM3];
    float* hs2 = (float*)smem;
    float* sgv = (float*)(smem + OFF_SGV);
    unsigned short* tab = (unsigned short*)(smem + OFF_TAB);
    float* red = (float*)(smem + OFF_RED);   // [4 waves][64]

    const int tid = threadIdx.x;
    const int bx = blockIdx.x;
    const int nb = bx % NBLK3;
    const int rem = bx / NBLK3;
    const int b = rem & 7;
    const int c = rem >> 3;
    const int t0 = c * CHUNK;
    const int lane = tid & 63, w = tid >> 6;

    if (tid < CHUNK) hs2[tid + 1] = dec[b * TT + t0 + tid];
    if (tid == 0) hs2[0] = (c == 0) ? y0[b] : dec[b * TT + t0 - 1];
    __syncthreads();
    build_table(tid, hs2, sgv, tab);
    __syncthreads();

    int ga[4], gb[4];
    float d[4], z[4];
    float gprev = sgv[0];
#pragma unroll
    for (int q = 0; q < 4; ++q) {
        int n = nb * 1024 + q * 256 + tid;
        float S = 0.f;
        if (n < N_MESH) {
            gb[q] = (int)(mesh[2 * n]     * 100.0f + 0.5f);
            ga[q] = (int)(mesh[2 * n + 1] * 100.0f + 0.5f);
            d[q]  = density[n];
            S = PQf[2 * (((size_t)(c * NB + b)) * NPAD + n)];
        } else { ga[q] = 0; gb[q] = 0; d[q] = 0.f; }
        z[q] = S - gprev;
    }

    float* pout = partials + ((size_t)((b * NBLK3 + nb) * 4 + w)) * TT + t0;

    for (int tb = 0; tb < CHUNK; tb += 16) {
        float v[16];
#pragma unroll
        for (int hh = 0; hh < 2; ++hh) {
            int tw = tb + hh * 8;
            u16x8 ra[4], rb[4];
#pragma unroll
            for (int q = 0; q < 4; ++q) {
                ra[q] = *(const u16x8*)&tab[ga[q] * TROW + tw];
                rb[q] = *(const u16x8*)&tab[gb[q] * TROW + tw];
            }
            float4 sA = *(const float4*)&sgv[tw];
            float4 sB = *(const float4*)&sgv[tw + 4];
            float sg8[8] = {sA.x, sA.y, sA.z, sA.w, sB.x, sB.y, sB.z, sB.w};
#pragma unroll
            for (int j = 0; j < 8; ++j) {
                float sgt = sg8[j];
                float dl = gprev - sgt;
                gprev = sgt;
                bool inc = sgt > 0.0f;
#pragma unroll
                for (int q = 0; q < 4; ++q) {
                    unsigned short u = inc ? ra[q][j] : rb[q][j];
                    float A = __half2float(__ushort_as_half(u));
                    z[q] = (z[q] + dl) * A;
                }
                float a0 = d[0] * z[0];
                float a1 = d[1] * z[1];
                a0 = fmaf(d[2], z[2], a0);
                a1 = fmaf(d[3], z[3], a1);
                v[hh * 8 + j] = a0 + a1;
            }
        }
        // 16-lane group sums on the VALU (DPP), zero DS
#pragma unroll
        for (int j = 0; j < 16; ++j) v[j] = dpp16_sum(v[j]);
        // cross-group (4) combine: one write + one b128 read, same-wave
        float outv = v[0];
#pragma unroll
        for (int j = 1; j < 16; ++j) if ((lane & 15) == j) outv = v[j];
        red[w * 64 + (lane & 15) * 4 + (lane >> 4)] = outv;
        if (lane < 16) {
            float4 s4 = *(const float4*)&red[w * 64 + lane * 4];
            pout[tb + lane] = (s4.x + s4.y) + (s4.z + s4.w);
        }
    }
}

// ---------------------------------------------------------------------------
// k4: outputs. m_t = (sum partials + g_t*D)/D ; plus broadcasts/copies.
// ---------------------------------------------------------------------------
__global__ __launch_bounds__(256) void k4_outputs(
    const float* __restrict__ partials, const float* __restrict__ sum_ptr,
    const float* __restrict__ density, const float* __restrict__ s0,
    const float* __restrict__ mesh, const float* __restrict__ dec,
    const float* __restrict__ y0, float* __restrict__ out)
{
    int i = blockIdx.x * blockDim.x + threadIdx.x;
    const int NM = NB * TT;
    if (i < NM) {
        int b = i >> 11, t = i & (TT - 1);
        float h  = dec[b * TT + t];
        float hp = t ? dec[b * TT + t - 1] : y0[b];
        float g  = (h >= hp) ? 1.0f : -1.0f;
        float acc = 0.f;
#pragma unroll 8
        for (int k = 0; k < NBLK3 * 4; ++k)
            acc += partials[((size_t)(b * NBLK3 * 4 + k)) * TT + t];
        float D = sum_ptr[0];
        float m = (acc + g * D) / D;
        out[OUT_M + i] = m;
        out[OUT_BNORM + i] = 0.5f * m + 0.5f;
        return;
    }
    int j = i - NM;
    const int n1 = NB * N_MESH;
    if (j < n1) {
        out[OUT_DENSB + j] = density[j % N_MESH];
    } else if (j < 2 * n1) {
        int jj = j - n1;
        out[OUT_S0 + jj] = s0[jj];
    } else if (j < 4 * n1) {
        int jj = j - 2 * n1;
        out[OUT_MESHB + jj] = mesh[jj % (2 * N_MESH)];
    }
}

extern "C" void kernel_launch(void* const* d_in, const int* in_sizes, int n_in,
                              void* d_out, int out_size, void* d_ws, size_t ws_size,
                              hipStream_t stream) {
    const float* dec  = (const float*)d_in[1];
    const float* s0   = (const float*)d_in[2];
    const float* y0   = (const float*)d_in[3];
    const float* mesh = (const float*)d_in[4];
    const float* Win  = (const float*)d_in[5];
    const float* bin  = (const float*)d_in[6];
    const float* Wblk = (const float*)d_in[7];
    const float* bblk = (const float*)d_in[8];
    const float* Wout = (const float*)d_in[9];
    const float* bout = (const float*)d_in[10];
    float* out = (float*)d_out;
    float* ws  = (float*)d_ws;

    float* ws_density  = ws + WS_DENSITY;
    float* ws_sum      = ws + WS_SUM;
    float* ws_partials = ws + WS_PART;
    float* ws_pq       = ws + WS_PQ;
    half8* WT          = (half8*)(ws + WS_PART);   // aliases partials (dead by k3)

    k1_scan1_prep<<<SCAN_GRID + PREP_NBLK, 256, 0, stream>>>(
        dec, y0, mesh, Wblk, (float2*)ws_pq, WT);
    k_mlp<<<MLP_NBLK, 512, 0, stream>>>(
        mesh, Win, bin, WT, bblk, Wout, bout, ws_density);
    k2_phase2_sum<<<dim3(25, NB), 256, 0, stream>>>(
        s0, ws_pq, ws_density, ws_sum);
    k3_phase3<<<SCAN_GRID, 256, 0, stream>>>(
        dec, y0, mesh, ws_density, ws_pq, ws_partials);
    {
        int total = NB * TT + NB * N_MESH * 4;   // 181216
        k4_outputs<<<(total + 255) / 256, 256, 0, stream>>>(
            ws_partials, ws_sum, ws_density, s0, mesh, dec, y0, out);
    }
}